// Round 6
// baseline (255.371 us; speedup 1.0000x reference)
//
#include <hip/hip_runtime.h>
#include <stdint.h>

// ---- problem constants (fixed by setup_inputs) ----
constexpr int NB   = 2;       // batch
constexpr int NN   = 13824;   // nodes = 6*48*48
constexpr int NE   = 55296;   // edges = 4*NN
constexpr int H    = 32;      // node hidden
constexpr int EHID = 64;      // edge hidden
constexpr int HH   = 1024;    // H*H
constexpr int TILE = 2304;    // 48*48 nodes per tile
constexpr int NXC  = 48;

typedef float f32x4 __attribute__((ext_vector_type(4)));
typedef short s16x8 __attribute__((ext_vector_type(8)));
typedef unsigned int u32x2 __attribute__((ext_vector_type(2)));
typedef __attribute__((address_space(3))) unsigned int as3_uint;

static __device__ __forceinline__ unsigned short f2bf(float f) {
    unsigned u = __float_as_uint(f);
    return (unsigned short)((u + 0x7fffu + ((u >> 16) & 1u)) >> 16);
}
static __device__ __forceinline__ unsigned packbf(float lo, float hi) {
    return (unsigned)f2bf(lo) | ((unsigned)f2bf(hi) << 16);
}
// single-instruction packed f32->bf16 (RNE), gfx950
static __device__ __forceinline__ unsigned cvtpk(float lo, float hi) {
    unsigned r;
    asm("v_cvt_pk_bf16_f32 %0, %1, %2" : "=v"(r) : "v"(lo), "v"(hi));
    return r;
}
static __device__ __forceinline__ float sigf(float v) {
    return 1.0f / (1.0f + __expf(-v));
}
static __device__ __forceinline__ float tanhfast(float v) {
    return 1.0f - 2.0f / (1.0f + __expf(2.0f * v));
}

// ---- fused pre-pass: aB | BpT | node projection | GRU weight bf16 ----
__global__ void __launch_bounds__(256)
k_pre(const float* __restrict__ ef, const float* __restrict__ eW1,
      const float* __restrict__ eb1, unsigned short* __restrict__ aB,
      const float* __restrict__ eW2, const float* __restrict__ eb2,
      unsigned short* __restrict__ BpT, float* __restrict__ eb2p,
      const float* __restrict__ in, const float* __restrict__ pW1,
      const float* __restrict__ pb1, const float* __restrict__ pW2,
      const float* __restrict__ pb2, float* __restrict__ S0,
      unsigned short* __restrict__ xb0,
      const float* __restrict__ gWih, const float* __restrict__ gWhh,
      unsigned short* __restrict__ gWb) {
    int blk = blockIdx.x;
    if (blk < 3456) {              // aB[e][k] = relu(ef@eW1+eb1) bf16, 4 k per thread
        int t = blk * 256 + threadIdx.x;
        int e = t >> 4, kq = (t & 15) * 4;
        float f0 = ef[e * 2], f1 = ef[e * 2 + 1];
        u32x2 w;
#pragma unroll
        for (int q = 0; q < 2; q++) {
            int k = kq + q * 2;
            float v0 = fmaxf(f0 * eW1[k]     + f1 * eW1[64 + k]     + eb1[k],     0.f);
            float v1 = fmaxf(f0 * eW1[k + 1] + f1 * eW1[64 + k + 1] + eb1[k + 1], 0.f);
            w[q] = packbf(v0, v1);
        }
        *(u32x2*)(aB + e * 64 + kq) = w;
    } else if (blk < 3520) {       // BpT[j'][k] = eW2[k][perm(j')]
        int t = (blk - 3456) * 256 + threadIdx.x;   // 16384 threads
        int jp = t >> 4, kq = (t & 15) * 4;
        int src_col = (jp & 31) * 32 + (jp >> 5);
        u32x2 w;
#pragma unroll
        for (int q = 0; q < 2; q++) {
            int k = kq + q * 2;
            w[q] = packbf(eW2[k * HH + src_col], eW2[(k + 1) * HH + src_col]);
        }
        *(u32x2*)(BpT + jp * 64 + kq) = w;
        if (kq == 0) eb2p[jp] = eb2[src_col];
    } else if (blk < 6976) {       // node projection
        int t = (blk - 3520) * 256 + threadIdx.x;
        int p = t >> 5;            // row m = b*NN + n
        int l = t & 31;
        float iv = (l < 16) ? in[p * 16 + l] : 0.f;
        float hid = pb1[l];
#pragma unroll
        for (int c = 0; c < 16; c++) hid = fmaf(__shfl(iv, c, 32), pW1[c * H + l], hid);
        hid = fmaxf(hid, 0.f);
        float out = pb2[l];
#pragma unroll
        for (int h = 0; h < 32; h++) out = fmaf(__shfl(hid, h, 32), pW2[h * H + l], out);
        S0[p * H + l]  = out;
        xb0[p * H + l] = f2bf(out);
    } else {                       // GRU weights: [96][32] Wih | [96][32] Whh
        int idx = (blk - 6976) * 256 + threadIdx.x;    // [0, 6144)
        gWb[idx] = f2bf(idx < 3072 ? gWih[idx] : gWhh[idx - 3072]);
    }
}

// ---- fully fused step: We GEMM (LDS) + NNConv + GRU, 16 nodes/block ----
// Per block: 64 edges (4 dirs x 16 nodes). Phase 1 recomputes We rows into a
// 64KB LDS half-tile (j' half per pass); phase 2 conv-MFMAs from LDS; phase 3
// GRU. We never touches global memory.
__global__ void __launch_bounds__(256)
k_fstep(const unsigned short* __restrict__ xb_in,   // [2][NN][32] bf16
        const float* __restrict__ h_in,             // [2][NN][32] f32
        const unsigned short* __restrict__ aB,      // [NE][64] bf16
        const unsigned short* __restrict__ Bp,      // [1024][64] bf16 (BpT)
        const float* __restrict__ eb2p,             // [1024] permuted bias
        const float* __restrict__ conv_b,
        const unsigned short* __restrict__ gWb,     // [96][32] Wih | [96][32] Whh
        const float* __restrict__ gbih, const float* __restrict__ gbhh,
        float* __restrict__ h_out, unsigned short* __restrict__ xb_out) {
    __shared__ unsigned char smem[65536 + 2048] __attribute__((aligned(16)));
    unsigned short* cvp = (unsigned short*)(smem + 65536);   // cv[2][16][32]

    const int tid  = threadIdx.x;
    const int wv   = tid >> 6;
    const int l    = tid & 63;
    const int cl   = l & 15;
    const int kg   = l >> 4;
    const int bsel = cl & 1;
    const int n0   = blockIdx.x * 16;
    const int tt   = n0 / TILE;
    const int i0   = n0 - tt * TILE;

    // ---- per-node neighbor indices (4 nodes per wave) ----
    int srcs[4][4];
#pragma unroll
    for (int u = 0; u < 4; ++u) {
        int n = n0 + wv * 4 + u;
        int i = n - tt * TILE;
        int r = i / NXC;
        int c = i - r * NXC;
        int bt = tt * TILE;
        int rm = (r == 0) ? NXC - 1 : r - 1;
        int rp = (r == NXC - 1) ? 0 : r + 1;
        int cm = (c == 0) ? NXC - 1 : c - 1;
        int cp = (c == NXC - 1) ? 0 : c + 1;
        srcs[u][0] = bt + rm * NXC + c;
        srcs[u][1] = bt + rp * NXC + c;
        srcs[u][2] = bt + r * NXC + cm;
        srcs[u][3] = bt + r * NXC + cp;
    }

    // ---- phase-1 B-operand: aB rows of this block's 64 edges (held in regs) ----
    s16x8 bfrag[4][2];
#pragma unroll
    for (int d = 0; d < 4; ++d) {
        const unsigned short* ap = aB + ((size_t)((tt * 4 + d) * TILE + i0 + cl)) * 64;
#pragma unroll
        for (int kk = 0; kk < 2; ++kk)
            bfrag[d][kk] = *(const s16x8*)(ap + kk * 32 + kg * 8);
    }

    f32x4 a[4][2] = {};   // conv accumulators: [node u][o-half]

#pragma unroll
    for (int half = 0; half < 2; ++half) {
        if (half == 1) __syncthreads();    // phase-2 reads of half 0 done

        // ---- phase 1: We GEMM -> LDS half-tile [64 e][512 j'] bf16 ----
#pragma unroll
        for (int it = 0; it < 8; ++it) {
            int jb = (wv * 8 + it) * 16;                 // j' base within half
            int jrow = half * 512 + jb + cl;             // global j' row
            s16x8 af0 = *(const s16x8*)(Bp + jrow * 64 + kg * 8);
            s16x8 af1 = *(const s16x8*)(Bp + jrow * 64 + 32 + kg * 8);
            f32x4 b4  = *(const f32x4*)(eb2p + half * 512 + jb + kg * 4);
            f32x4 acc[4] = {};
#pragma unroll
            for (int d = 0; d < 4; ++d) {
                acc[d] = __builtin_amdgcn_mfma_f32_16x16x32_bf16(af0, bfrag[d][0], acc[d], 0, 0, 0);
                acc[d] = __builtin_amdgcn_mfma_f32_16x16x32_bf16(af1, bfrag[d][1], acc[d], 0, 0, 0);
            }
#pragma unroll
            for (int d = 0; d < 4; ++d) {
                int el = d * 16 + cl;
                int L  = el * 1024 + (jb + kg * 4) * 2;
                int ph = L ^ ((el & 7) << 4);
                u32x2 w;
                w[0] = cvtpk(acc[d][0] + b4[0], acc[d][1] + b4[1]);
                w[1] = cvtpk(acc[d][2] + b4[2], acc[d][3] + b4[3]);
                *(u32x2*)(smem + ph) = w;
            }
        }
        __syncthreads();

        // ---- phase 2: conv MFMA from LDS (o-half = half) ----
#pragma unroll
        for (int d = 0; d < 4; ++d) {
#pragma unroll
            for (int u = 0; u < 4; ++u) {
                int rl = d * 16 + (wv * 4 + u);
                int ph = (rl * 1024 + cl * 64 + kg * 16) ^ ((rl & 7) << 4);
                s16x8 af  = *(const s16x8*)(smem + ph);
                s16x8 bfr = *(const s16x8*)(xb_in + ((size_t)(bsel * NN + srcs[u][d])) * 32 + kg * 8);
                a[u][half] = __builtin_amdgcn_mfma_f32_16x16x32_bf16(af, bfr, a[u][half], 0, 0, 0);
            }
        }
    }

    // ---- conv epilogue: relu(+bias) -> cv LDS (bf16) ----
    f32x4 cb0 = *(const f32x4*)(conv_b + kg * 4);
    f32x4 cb1 = *(const f32x4*)(conv_b + 16 + kg * 4);
    if (cl < 2) {                  // batch = cl; rows o = kg*4+r (half0) / 16+kg*4+r (half1)
#pragma unroll
        for (int u = 0; u < 4; ++u) {
            int nl = wv * 4 + u;
            unsigned* cp32 = (unsigned*)&cvp[(cl * 16 + nl) * 32];
            cp32[kg * 2]     = cvtpk(fmaxf(a[u][0][0] + cb0[0], 0.f), fmaxf(a[u][0][1] + cb0[1], 0.f));
            cp32[kg * 2 + 1] = cvtpk(fmaxf(a[u][0][2] + cb0[2], 0.f), fmaxf(a[u][0][3] + cb0[3], 0.f));
            cp32[8 + kg * 2]     = cvtpk(fmaxf(a[u][1][0] + cb1[0], 0.f), fmaxf(a[u][1][1] + cb1[1], 0.f));
            cp32[8 + kg * 2 + 1] = cvtpk(fmaxf(a[u][1][2] + cb1[2], 0.f), fmaxf(a[u][1][3] + cb1[3], 0.f));
        }
    }
    __syncthreads();

    // ---- phase 3: GRU, waves 0/1 = batch 0/1 (16 m-rows each) ----
    if (wv < 2) {
        s16x8 ax = *(const s16x8*)(cvp + (wv * 16 + cl) * 32 + kg * 8);
        s16x8 ah = *(const s16x8*)(xb_in + ((size_t)wv * NN + n0 + cl) * 32 + kg * 8);

        f32x4 accx[6], acch[6];
#pragma unroll
        for (int jb = 0; jb < 6; ++jb) {
            s16x8 wx = *(const s16x8*)(gWb + (jb * 16 + cl) * 32 + kg * 8);
            s16x8 wh = *(const s16x8*)(gWb + 3072 + (jb * 16 + cl) * 32 + kg * 8);
            f32x4 z0 = {};
            f32x4 z1 = {};
            accx[jb] = __builtin_amdgcn_mfma_f32_16x16x32_bf16(ax, wx, z0, 0, 0, 0);
            acch[jb] = __builtin_amdgcn_mfma_f32_16x16x32_bf16(ah, wh, z1, 0, 0, 0);
        }

        float bihR[2] = {gbih[cl],      gbih[16 + cl]};
        float bihZ[2] = {gbih[32 + cl], gbih[48 + cl]};
        float bihN[2] = {gbih[64 + cl], gbih[80 + cl]};
        float bhhR[2] = {gbhh[cl],      gbhh[16 + cl]};
        float bhhZ[2] = {gbhh[32 + cl], gbhh[48 + cl]};
        float bhhN[2] = {gbhh[64 + cl], gbhh[80 + cl]};

#pragma unroll
        for (int hb = 0; hb < 2; ++hb) {
#pragma unroll
            for (int ri = 0; ri < 4; ++ri) {
                int rrow = kg * 4 + ri;
                size_t m = (size_t)wv * NN + n0 + rrow;
                float rg = sigf(accx[hb][ri] + acch[hb][ri] + bihR[hb] + bhhR[hb]);
                float zg = sigf(accx[2 + hb][ri] + acch[2 + hb][ri] + bihZ[hb] + bhhZ[hb]);
                float ng = tanhfast((accx[4 + hb][ri] + bihN[hb]) +
                                    rg * (acch[4 + hb][ri] + bhhN[hb]));
                float ho = h_in[m * 32 + hb * 16 + cl];
                float hn = fmaf(zg, ho - ng, ng);
                h_out[m * 32 + hb * 16 + cl]  = hn;
                xb_out[m * 32 + hb * 16 + cl] = f2bf(hn);
            }
        }
    }
}

extern "C" void kernel_launch(void* const* d_in, const int* in_sizes, int n_in,
                              void* d_out, int out_size, void* d_ws, size_t ws_size,
                              hipStream_t stream) {
    const float* in_nodes = (const float*)d_in[0];
    const float* ef       = (const float*)d_in[1];
    const float* pW1      = (const float*)d_in[4];
    const float* pb1      = (const float*)d_in[5];
    const float* pW2      = (const float*)d_in[6];
    const float* pb2      = (const float*)d_in[7];
    const float* eW1      = (const float*)d_in[8];
    const float* eb1      = (const float*)d_in[9];
    const float* eW2      = (const float*)d_in[10];
    const float* eb2      = (const float*)d_in[11];
    const float* convb    = (const float*)d_in[12];
    const float* gWih     = (const float*)d_in[13];
    const float* gWhh     = (const float*)d_in[14];
    const float* gbih     = (const float*)d_in[15];
    const float* gbhh     = (const float*)d_in[16];

    unsigned char* ws = (unsigned char*)d_ws;
    unsigned short* aB   = (unsigned short*)(ws + 0ull);          //  7077888 B
    unsigned short* BpT  = (unsigned short*)(ws + 7077888ull);    //   131072 B
    float*          eb2p = (float*)         (ws + 7208960ull);    //     4096 B
    float*          S0   = (float*)         (ws + 7213056ull);    //  3538944 B
    float*          S1   = (float*)         (ws + 10752000ull);   //  3538944 B
    unsigned short* xb0  = (unsigned short*)(ws + 14290944ull);   //  1769472 B
    unsigned short* xb1  = (unsigned short*)(ws + 16060416ull);   //  1769472 B
    unsigned short* gWb  = (unsigned short*)(ws + 17829888ull);   //    12288 B

    k_pre<<<7000, 256, 0, stream>>>(ef, eW1, eb1, aB, eW2, eb2, BpT, eb2p,
                                    in_nodes, pW1, pb1, pW2, pb2, S0, xb0,
                                    gWih, gWhh, gWb);

    float* out = (float*)d_out;
    k_fstep<<<NN / 16, 256, 0, stream>>>(xb0, S0, aB, BpT, eb2p, convb, gWb,
                                         gbih, gbhh, S1, xb1);
    k_fstep<<<NN / 16, 256, 0, stream>>>(xb1, S1, aB, BpT, eb2p, convb, gWb,
                                         gbih, gbhh, S0, xb0);
    k_fstep<<<NN / 16, 256, 0, stream>>>(xb0, S0, aB, BpT, eb2p, convb, gWb,
                                         gbih, gbhh, S1, xb1);
    k_fstep<<<NN / 16, 256, 0, stream>>>(xb1, S1, aB, BpT, eb2p, convb, gWb,
                                         gbih, gbhh, out, xb0);
}